// Round 18
// baseline (36.330 us; speedup 1.0000x reference)
//
#include <hip/hip_runtime.h>

// Smith-Waterman soft-DP, B=512, x: (512,151,151) f32, scalar output.
// ROW-SCAN formulation (150 row iterations). h1's along-row recurrence is
// solved by a weighted DPP prefix scan; h0/h2/score are prev-row FMAs.
// Lane packing c = 3*lane + k. Linear domain H = exp(h)*2^-E.
// x staged as e5m2 bytes in LDS, GROUPED layout [g][lane][4 rows x 4B]
// (38x1024B): DP does ONE ds_read_b128 per 4 rows, double-buffered GE/GO,
// consumed >=3 rows after issue (LDS latency fully hidden).
// 512 blocks x 256 threads; waves 1-3 stage then exit; wave 0 runs DP.

#define CGO 6.737946999085467e-03f   // e^-5
#define CGE 3.678794411714423e-01f   // e^-1
#define L2E 1.4426950408889634f
#define LN2 0.6931471805599453f
#define RTHR 0x1p28f
#define RSC  0x1p-64f
#define EADD 64.0f

// scan constants: A = e^-3 (per-lane carry factor, 3 cells/lane)
#define SA1 4.9787068367863944e-02f   // e^-3
#define SA2 2.4787521766663585e-03f   // e^-6
#define SA4 6.1442123533282098e-06f   // e^-12
#define SA8 3.7751345442790977e-11f   // e^-24
#define CA1 3.6787944117144233e-01f   // e^-1
#define CA2 1.3533528323661270e-01f   // e^-2
#define CA3 4.9787068367863944e-02f   // e^-3

#if __has_builtin(__builtin_amdgcn_exp2f)
#define EXP2(x) __builtin_amdgcn_exp2f(x)
#else
static __device__ __forceinline__ float EXP2_(float x){float r;asm("v_exp_f32 %0, %1":"=v"(r):"v"(x));return r;}
#define EXP2(x) EXP2_(x)
#endif

#if __has_builtin(__builtin_amdgcn_logf)
#define LOG2(x) __builtin_amdgcn_logf(x)
#else
static __device__ __forceinline__ float LOG2_(float x){float r;asm("v_log_f32 %0, %1":"=v"(r):"v"(x));return r;}
#define LOG2(x) LOG2_(x)
#endif

#define DPP_UP   0x138   // wave_shr:1 (lane i <- i-1; lane 0 -> bound)
#define DPP_DN   0x130   // wave_shl:1 (lane i <- i+1; lane 63 -> bound)
#define ROW_SHR1 0x111
#define ROW_SHR2 0x112
#define ROW_SHR4 0x114
#define ROW_SHR8 0x118
#define BCAST15  0x142
#define BCAST31  0x143

template<int CTRL>
static __device__ __forceinline__ float dppz(float v){   // invalid lanes -> 0
    return __int_as_float(__builtin_amdgcn_update_dpp(
        0, __float_as_int(v), CTRL, 0xF, 0xF, true));
}
template<int CTRL>
static __device__ __forceinline__ float dppc(float old, float v){ // invalid -> old
    return __int_as_float(__builtin_amdgcn_update_dpp(
        __float_as_int(old), __float_as_int(v), CTRL, 0xF, 0xF, false));
}

// decode: low 16 bits interpreted as f16 -> f32
static __device__ __forceinline__ float dec16(unsigned bits16){
    unsigned short us = (unsigned short)bits16;
    _Float16 h;
    __builtin_memcpy(&h, &us, 2);
    return (float)h;
}

// ---- one row step (row r). Entry: SX[k] = exp(x[r, 3l+k]); Rcur = e5m2
// dword of row r+1 (from GE/GO, loaded >=3 rows ago); HSsP[k] =
// hs(r-1, c-1) + oneE (shifted, pre-added); g/h2p = prev-row state.
static __device__ __forceinline__
void stepRow(const unsigned Rcur, const float vA16, const float vA32,
             float (&SX)[3], float (&HSsP)[3], float (&g)[3], float (&h2p)[3],
             const float oneE, float (&S)[3])
{
    // decode row r+1 (x2 for this row; sx for next row)
    const float D0 = dec16(Rcur << 8);
    const float D1 = dec16(Rcur & 0xFF00u);
    const float D2 = dec16((Rcur >> 8) & 0xFF00u);
    const float D3 = dppz<DPP_DN>(D0);          // byte0 of lane+1

    // h0(r,c) = sx * (hs(r-1,c-1) + oneE)   [pre-added]
    const float h00 = SX[0] * HSsP[0];
    const float h01 = SX[1] * HSsP[1];
    const float h02 = SX[2] * HSsP[2];

    // b(c) = CGO * h0(r, c-1)
    const float h0u = dppz<DPP_UP>(h02);
    const float b0 = CGO * h0u;
    const float b1 = CGO * h00;
    const float b2 = CGO * h01;

    // local prefix within lane (cells k=0,1,2)
    const float p1 = fmaf(CGE, b0, b1);
    const float p2 = fmaf(CGE, p1, b2);

    // cross-lane exclusive weighted scan of lane totals (factor A=e^-3)
    float t = dppz<DPP_UP>(p2);
    t = fmaf(SA1, dppz<ROW_SHR1>(t), t);
    t = fmaf(SA2, dppz<ROW_SHR2>(t), t);
    t = fmaf(SA4, dppz<ROW_SHR4>(t), t);
    t = fmaf(SA8, dppz<ROW_SHR8>(t), t);
    t = fmaf(vA16, dppz<BCAST15>(t), t);
    t = fmaf(vA32, dppz<BCAST31>(t), t);

    // h1_k = p_k + CGE^{k+1} * C
    const float h10 = fmaf(CA1, t, b0);
    const float h11 = fmaf(CA2, t, p1);
    const float h12 = fmaf(CA3, t, p2);

    // h2(r,c) = CGO*(h0+h1)(r-1,c) + CGE*h2(r-1,c)
    const float h20 = fmaf(CGO, g[0], CGE * h2p[0]);
    const float h21 = fmaf(CGO, g[1], CGE * h2p[1]);
    const float h22 = fmaf(CGO, g[2], CGE * h2p[2]);

    // g = h0+h1; hs = g+h2
    g[0] = h00 + h10; g[1] = h01 + h11; g[2] = h02 + h12;
    const float hs0 = g[0] + h20;
    const float hs1 = g[1] + h21;
    const float hs2 = g[2] + h22;
    h2p[0] = h20; h2p[1] = h21; h2p[2] = h22;

    // score: x2(r,c) = exp(x[r+1, c+1]) = (D1, D2, D3); stored zeros gate
    S[0] = fmaf(D1, hs0, S[0]);
    S[1] = fmaf(D2, hs1, S[1]);
    S[2] = fmaf(D3, hs2, S[2]);

    // next-row prep (pre-add oneE; lane-0 boundary supplies oneE exactly)
    HSsP[0] = dppc<DPP_UP>(oneE, hs2 + oneE);
    HSsP[1] = hs0 + oneE;
    HSsP[2] = hs1 + oneE;
    SX[0] = D0; SX[1] = D1; SX[2] = D2;
}

__global__ __launch_bounds__(256)
void sw_row4(const float* __restrict__ x, float* __restrict__ part,
             float* __restrict__ out_atomic, int use_atomic) {
    const int b = blockIdx.x;
    const float* xb = x + (size_t)b * 22801;
    const int tid = threadIdx.x;

    __shared__ char ldsB[38912];   // 38 groups x 64 lanes x 16B (4 rows x 4B)

    // ---- phase A0: zero-init (all 4 waves) ----
    {
        int4* l4 = (int4*)ldsB;
        for (int i = tid; i < 38912 / 16; i += 256) l4[i] = int4{0,0,0,0};
    }
    __syncthreads();

    // ---- phase A1: coalesced load + exp -> e5m2 byte scatter ----
    // cell (r,c) -> byte (r>>2)*1024 + (c/3)*16 + (r&3)*4 + c%3
    for (int i = 0; i < 90; ++i) {
        const int idx = i * 256 + tid;
        const int idc = idx > 22800 ? 22800 : idx;
        const float v = EXP2(xb[idc] * L2E);
        const _Float16 hv = (_Float16)v;          // RNE f32->f16
        unsigned short u16; __builtin_memcpy(&u16, &hv, 2);
        const unsigned byte = ((unsigned)u16 + 0x7Fu + ((u16 >> 8) & 1u)) >> 8;
        const unsigned r = ((unsigned)idc * 111111u) >> 24;   // idc / 151
        const int c = idc - 151 * (int)r;
        const int l3 = (c * 0x5556) >> 16;        // c / 3
        const int kk = c - 3 * l3;
        ldsB[(int)(r >> 2) * 1024 + l3 * 16 + (int)(r & 3u) * 4 + kk] = (char)byte;
    }
    __syncthreads();
    if (tid >= 64) return;                        // waves 1-3 done

    // ---- phase B: DP on wave 0 ----
    const int lane = tid;
    const float vA16 = EXP2(-4.3280851226668902f * (float)((lane & 15) + 1));
    const float vA32 = EXP2(-4.3280851226668902f * (float)((lane & 31) + 1));
    const char* gbase = ldsB + 16 * lane;

    uint4 GE = *(const uint4*)(gbase);            // group 0 (rows 0-3)
    uint4 GO = *(const uint4*)(gbase + 1024);     // group 1 (rows 4-7)

    float SX[3];
    SX[0] = dec16(GE.x << 8);
    SX[1] = dec16(GE.x & 0xFF00u);
    SX[2] = dec16((GE.x >> 8) & 0xFF00u);

    float HSsP[3] = {1.0f, 1.0f, 1.0f};   // hs(-1)=0 -> oneE everywhere
    float g[3]   = {0.0f, 0.0f, 0.0f};
    float h2p[3] = {0.0f, 0.0f, 0.0f};
    float S[3]   = {0.0f, 0.0f, 0.0f};
    float oneE = 1.0f;   // 2^-E
    float E = 0.0f;

    for (int gi = 0; gi < 18; ++gi) {   // rows 8gi .. 8gi+7
        stepRow(GE.y, vA16, vA32, SX, HSsP, g, h2p, oneE, S);   // row 8gi
        stepRow(GE.z, vA16, vA32, SX, HSsP, g, h2p, oneE, S);
        stepRow(GE.w, vA16, vA32, SX, HSsP, g, h2p, oneE, S);
        stepRow(GO.x, vA16, vA32, SX, HSsP, g, h2p, oneE, S);
        GE = *(const uint4*)(gbase + (2 * gi + 2) * 1024);      // rows 8gi+8..11
        stepRow(GO.y, vA16, vA32, SX, HSsP, g, h2p, oneE, S);
        stepRow(GO.z, vA16, vA32, SX, HSsP, g, h2p, oneE, S);
        stepRow(GO.w, vA16, vA32, SX, HSsP, g, h2p, oneE, S);   // row 8gi+6
        // renorm decision from row 8gi+6 state; applied after row 8gi+7.
        // Safety: RTHR=2^28, worst growth ~2^8.2/row -> <=2^102 at apply.
        float m = fmaxf(fmaxf(g[0], g[1]), g[2]);
        m = fmaxf(m, fmaxf(fmaxf(h2p[0], h2p[1]), h2p[2]));
        const bool rn = __any(m > RTHR);
        const float sc = rn ? RSC : 1.0f;
        stepRow(GE.x, vA16, vA32, SX, HSsP, g, h2p, oneE, S);   // row 8gi+7
        GO = *(const uint4*)(gbase + (2 * gi + 3) * 1024);      // rows 8gi+12..15
        #pragma unroll
        for (int k = 0; k < 3; ++k) {
            HSsP[k] *= sc; g[k] *= sc; h2p[k] *= sc; S[k] *= sc;
        }
        oneE *= sc; E += rn ? EADD : 0.0f;
    }
    // tail rows 144-149 (GE = group 36, GO = group 37; rows 150-151 zero pad)
    stepRow(GE.y, vA16, vA32, SX, HSsP, g, h2p, oneE, S);   // row 144
    stepRow(GE.z, vA16, vA32, SX, HSsP, g, h2p, oneE, S);
    stepRow(GE.w, vA16, vA32, SX, HSsP, g, h2p, oneE, S);
    stepRow(GO.x, vA16, vA32, SX, HSsP, g, h2p, oneE, S);
    stepRow(GO.y, vA16, vA32, SX, HSsP, g, h2p, oneE, S);
    stepRow(GO.z, vA16, vA32, SX, HSsP, g, h2p, oneE, S);   // row 149

    // wave sum of S (E uniform across lanes)
    float St = (S[0] + S[1]) + S[2];
    #pragma unroll
    for (int off = 32; off; off >>= 1) St += __shfl_xor(St, off, 64);
    if (lane == 0) {
        const float val = LN2 * (E + LOG2(St));
        if (use_atomic) atomicAdd(out_atomic, val);
        else            part[b] = val;
    }
}

__global__ __launch_bounds__(256)
void final_reduce(const float* __restrict__ part, float* __restrict__ out) {
    const int t = threadIdx.x;
    float v = part[t] + part[t + 256];
    #pragma unroll
    for (int off = 32; off; off >>= 1) v += __shfl_xor(v, off);
    __shared__ float ws[4];
    if ((t & 63) == 0) ws[t >> 6] = v;
    __syncthreads();
    if (t == 0) out[0] = ws[0] + ws[1] + ws[2] + ws[3];
}

extern "C" void kernel_launch(void* const* d_in, const int* in_sizes, int n_in,
                              void* d_out, int out_size, void* d_ws, size_t ws_size,
                              hipStream_t stream) {
    const float* x = (const float*)d_in[0];
    float* out = (float*)d_out;

    if (ws_size >= 512 * sizeof(float)) {
        float* part = (float*)d_ws;
        sw_row4<<<512, 256, 0, stream>>>(x, part, nullptr, 0);
        final_reduce<<<1, 256, 0, stream>>>(part, out);
    } else {
        hipMemsetAsync(out, 0, sizeof(float), stream);
        sw_row4<<<512, 256, 0, stream>>>(x, nullptr, out, 1);
    }
}